// Round 9
// baseline (11.531 us; speedup 1.0000x reference)
//
#include <hip/hip_runtime.h>
#include <math.h>

#define HDIM 1024
#define BATCH 8
#define SEQ 4096

// d_ws layout: f32 wpart[1024] (one per k1 block) | i32 dotp[4][8][1024]

__global__ __launch_bounds__(256) void k1(const float* __restrict__ hs,
                                          const float* __restrict__ W,
                                          float* __restrict__ wpart,
                                          int* __restrict__ dotp) {
    __shared__ float swabs[4];
    const int tid = threadIdx.x;
    const int wave = tid >> 6, lane = tid & 63;
    const int gw = blockIdx.x * 4 + wave;   // 0..4095
    const int o = gw & (HDIM - 1);          // output row
    const int part = gw >> 10;              // 0..3 quarter of the H dim
    const int h0 = part * 256 + lane * 4;

    float4 wv = *reinterpret_cast<const float4*>(W + (size_t)o * HDIM + h0);
    const float we[4] = {wv.x, wv.y, wv.z, wv.w};

    float xe[BATCH][4];
    #pragma unroll
    for (int b = 0; b < BATCH; ++b) {
        float4 xv = *reinterpret_cast<const float4*>(hs + (size_t)b * SEQ * HDIM + h0);
        xe[b][0] = xv.x; xe[b][1] = xv.y; xe[b][2] = xv.z; xe[b][3] = xv.w;
    }

    float aabs = 0.f;
    int n[BATCH], d[BATCH];
    #pragma unroll
    for (int b = 0; b < BATCH; ++b) { n[b] = 0; d[b] = 0; }

    #pragma unroll
    for (int j = 0; j < 4; ++j) {
        unsigned long long wsg = __ballot(we[j] < 0.f);
        unsigned long long wnz = __ballot(we[j] != 0.f);
        aabs += fabsf(we[j]);
        #pragma unroll
        for (int b = 0; b < BATCH; ++b) {
            unsigned long long u = wnz & __ballot(xe[b][j] != 0.f);
            unsigned long long m = (wsg ^ __ballot(xe[b][j] < 0.f)) & u;
            n[b] += __popcll(u);
            d[b] += __popcll(m);
        }
    }

    #pragma unroll
    for (int off = 32; off >= 1; off >>= 1) aabs += __shfl_down(aabs, off, 64);
    if (lane == 0) {
        swabs[wave] = aabs;
        #pragma unroll
        for (int b = 0; b < BATCH; ++b)
            dotp[(part * BATCH + b) * HDIM + o] = n[b] - 2 * d[b];
    }
    __syncthreads();
    if (tid == 0) wpart[blockIdx.x] = swabs[0] + swabs[1] + swabs[2] + swabs[3];
}

__global__ __launch_bounds__(256) void k2(const int* __restrict__ dotp,
                                          const float* __restrict__ wpart,
                                          const float* __restrict__ bias,
                                          const float* __restrict__ alpha,
                                          float* __restrict__ out) {
    __shared__ float wsum[4];
    const int tid = threadIdx.x;
    const int wave = tid >> 6, lane = tid & 63;

    // issue the output-side loads early so they overlap the reduction
    const int idx = blockIdx.x * 256 + tid;   // b*1024 + o
    const int b = idx >> 10, o = idx & (HDIM - 1);
    int d0 = dotp[(0 * BATCH + b) * HDIM + o];
    int d1 = dotp[(1 * BATCH + b) * HDIM + o];
    int d2 = dotp[(2 * BATCH + b) * HDIM + o];
    int d3 = dotp[(3 * BATCH + b) * HDIM + o];
    float bo = bias[o];
    float a = alpha[0];

    float s = wpart[tid] + wpart[tid + 256] + wpart[tid + 512] + wpart[tid + 768];
    #pragma unroll
    for (int off = 32; off >= 1; off >>= 1) s += __shfl_down(s, off, 64);
    if (lane == 0) wsum[wave] = s;
    __syncthreads();
    const float tot = wsum[0] + wsum[1] + wsum[2] + wsum[3];

    if (a < 1e-5f) a = 1e-5f;
    const float scale = a * tot * (1.0f / 1048576.0f);
    out[idx] = tanhf(scale * (float)(d0 + d1 + d2 + d3) + bo);
}

extern "C" void kernel_launch(void* const* d_in, const int* in_sizes, int n_in,
                              void* d_out, int out_size, void* d_ws, size_t ws_size,
                              hipStream_t stream) {
    const float* hs    = (const float*)d_in[0];
    const float* W     = (const float*)d_in[1];
    const float* bias  = (const float*)d_in[2];
    const float* alpha = (const float*)d_in[3];
    float* out = (float*)d_out;

    float* wpart = (float*)d_ws;                 // 1024 floats (per k1 block)
    int* dotp = (int*)(wpart + 1024);            // 4*8*1024 ints

    k1<<<1024, 256, 0, stream>>>(hs, W, wpart, dotp);
    k2<<<(BATCH * HDIM) / 256, 256, 0, stream>>>(dotp, wpart, bias, alpha, out);
}